// Round 2
// baseline (142602.222 us; speedup 1.0000x reference)
//
#include <hip/hip_runtime.h>
#include <hip/hip_bf16.h>

// Problem constants
#define NB 64
#define NT 600
#define NTC 50
#define NH 400
#define NKATT 10
#define NALPHA 60
#define NOUT 121

typedef unsigned short u16;

// ---- canonical f32 weight/input pool (device global, filled by k_convert) ----
#define O_INP   0          // [64][600][3]        115200
#define O_WIH1  115200     // [1600][63]          100800
#define O_BIH1  216000     // 1600
#define O_WHH1  217600     // [1600][400]         640000
#define O_BHH1  857600     // 1600
#define O_WIH2  859200     // [1600][463]         740800
#define O_BIH2  1600000    // 1600
#define O_WHH2  1601600    // 640000
#define O_BHH2  2241600    // 1600
#define O_WIH3  2243200    // [1600][863]         1380800
#define O_BIH3  3624000    // 1600
#define O_WHH3  3625600    // 640000
#define O_BHH3  4265600    // 1600
#define O_WATT  4267200    // [30][400]           12000
#define O_BATT  4279200    // 30
#define O_WGMM  4279230    // [121][1200]         145200
#define O_BGMM  4424430    // 121
#define GW_FLOATS 4424551

// ---- state layout (device global, zeroed by k_convert each call) ----
#define H1OFF 0            // [2][NB][NH] ping-pong
#define H2OFF 51200
#define H3OFF 102400
#define C1OFF 153600       // [NB][NH] owner-exclusive in-place
#define C2OFF 179200
#define C3OFF 204800
#define KPOFF 230400       // [2][NB][NKATT] ping-pong
#define WINOFF 231680      // [NB][NALPHA]
#define ST_FLOATS 235520

__device__ float g_W[GW_FLOATS];
__device__ float g_state[ST_FLOATS];
__device__ int   g_isf32;

__device__ __forceinline__ float bf2f(u16 v) {
    union { unsigned int u; float f; } t; t.u = ((unsigned int)v) << 16; return t.f;
}
__device__ __forceinline__ u16 f2bf(float f) {
    union { float ff; unsigned int u; } t; t.ff = f;
    unsigned int lsb = (t.u >> 16) & 1u;
    t.u += 0x7fffu + lsb;   // round-to-nearest-even
    return (u16)(t.u >> 16);
}
__device__ __forceinline__ float sigm(float x) { return 1.f / (1.f + expf(-x)); }

// ---- dtype probe: even-index u16s of an f32 tensor are mantissa garbage ----
__global__ void k_detect(const void* whh1) {
    if (threadIdx.x == 0 && blockIdx.x == 0) {
        const u16* p = (const u16*)whh1;
        int f32 = 0;
        for (int k = 0; k < 256; ++k) {
            float v = bf2f(p[2 * k]);
            if (!(fabsf(v) < 1e3f)) f32 = 1;   // catches huge AND NaN
        }
        g_isf32 = f32;
    }
}

// ---- canonicalize all float tensors to f32 in g_W; zero state ----
__global__ void k_convert(const void* inp,
                          const void* wih1, const void* bih1, const void* whh1, const void* bhh1,
                          const void* wih2, const void* bih2, const void* whh2, const void* bhh2,
                          const void* wih3, const void* bih3, const void* whh3, const void* bhh3,
                          const void* watt, const void* batt, const void* wgmm, const void* bgmm)
{
    const int gt = blockIdx.x * blockDim.x + threadIdx.x;
    const int gs = gridDim.x * blockDim.x;
    const int f32 = g_isf32;
#define CVT(src, off, n) \
    for (int i = gt; i < (n); i += gs) \
        g_W[(off) + i] = f32 ? ((const float*)(src))[i] : bf2f(((const u16*)(src))[i]);
    CVT(inp,  O_INP,  115200)
    CVT(wih1, O_WIH1, 100800)  CVT(bih1, O_BIH1, 1600)
    CVT(whh1, O_WHH1, 640000)  CVT(bhh1, O_BHH1, 1600)
    CVT(wih2, O_WIH2, 740800)  CVT(bih2, O_BIH2, 1600)
    CVT(whh2, O_WHH2, 640000)  CVT(bhh2, O_BHH2, 1600)
    CVT(wih3, O_WIH3, 1380800) CVT(bih3, O_BIH3, 1600)
    CVT(whh3, O_WHH3, 640000)  CVT(bhh3, O_BHH3, 1600)
    CVT(watt, O_WATT, 12000)   CVT(batt, O_BATT, 30)
    CVT(wgmm, O_WGMM, 145200)  CVT(bgmm, O_BGMM, 121)
#undef CVT
    for (int i = gt; i < ST_FLOATS; i += gs) g_state[i] = 0.f;
}

// ---- GMM output head for step tOut (reads h parity tOut&1) ----
__device__ void out_block(void* out, int tOut, int b0, int tid,
                          float (*z_s)[1200], float (*zv_s)[121])
{
    const int pp = tOut & 1;
    for (int i = tid; i < 4 * 1200; i += 512) {
        int bl = i / 1200, k = i - bl * 1200; int b = b0 + bl;
        float v;
        if (k < 400)      v = g_state[H1OFF + pp * (NB * NH) + b * NH + k];
        else if (k < 800) v = g_state[H2OFF + pp * (NB * NH) + b * NH + (k - 400)];
        else              v = g_state[H3OFF + pp * (NB * NH) + b * NH + (k - 800)];
        z_s[bl][k] = v;
    }
    __syncthreads();
    if (tid < 484) {
        int bl = tid / 121, row = tid - bl * 121;
        float acc = g_W[O_BGMM + row];
        const float* w = g_W + O_WGMM + row * 1200;
        const float* zp = z_s[bl];
        for (int k = 0; k < 1200; ++k) acc += w[k] * zp[k];
        zv_s[bl][row] = acc;
    }
    __syncthreads();
    if (tid < 484) {
        int bl = tid / 121, jo = tid - bl * 121;
        const float* zv = zv_s[bl];
        float val;
        if (jo < 20) {                        // softmax(pi_hat = z[1:21])
            float m = -1e30f;
            for (int i = 0; i < 20; ++i) m = fmaxf(m, zv[1 + i]);
            float s = 0.f;
            for (int i = 0; i < 20; ++i) s += expf(zv[1 + i] - m);
            val = expf(zv[1 + jo] - m) / s;
        } else if (jo < 60)  val = zv[jo + 1];          // mus
        else if (jo < 100)   val = expf(zv[jo + 1]);    // exp(sig_hat)
        else if (jo < 120)   val = tanhf(zv[jo + 1]);   // tanh(rho_hat)
        else                 val = 1.f / (1.f + expf(-zv[0]));  // sigmoid(e_hat)
        int idx = ((b0 + bl) * NT + tOut) * NOUT + jo;
        if (g_isf32) ((float*)out)[idx] = val;
        else         ((u16*)out)[idx]  = f2bf(val);
    }
}

// ---- K1: LSTM1 (input=[window(t-1), x_t], K=63+400) + fused output head (t-1) ----
__global__ __launch_bounds__(512) void k_step1(void* out, int t)
{
    const int tid = threadIdx.x;
    const int cur = t & 1, prev = 1 - cur;
    if (blockIdx.y < 8) {
        __shared__ float in_s[8][64];
        __shared__ float h_s[8][400];
        __shared__ float gate_s[8][64];
        const int b0 = blockIdx.y * 8;
        const int j0 = blockIdx.x * 16;
        for (int i = tid; i < 8 * 63; i += 512) {
            int bl = i / 63, k = i - bl * 63; int b = b0 + bl;
            in_s[bl][k] = (k < 60) ? g_state[WINOFF + b * NALPHA + k]
                                   : g_W[O_INP + (b * NT + t) * 3 + (k - 60)];
        }
        for (int i = tid; i < 8 * 400; i += 512) {
            int bl = i / 400, k = i - bl * 400;
            h_s[bl][k] = g_state[H1OFF + prev * (NB * NH) + (b0 + bl) * NH + k];
        }
        __syncthreads();
        {
            const int bl = tid >> 6, r = tid & 63, jl = r >> 2, g = r & 3;
            const int row = g * NH + j0 + jl;
            float acc = g_W[O_BIH1 + row] + g_W[O_BHH1 + row];
            const float* wi = g_W + O_WIH1 + row * 63;
            const float* wh = g_W + O_WHH1 + row * NH;
            const float* ip = in_s[bl];
            const float* hp = h_s[bl];
            for (int k = 0; k < 63; ++k) acc += wi[k] * ip[k];
            #pragma unroll 4
            for (int k = 0; k < 400; ++k) acc += wh[k] * hp[k];
            gate_s[bl][r] = acc;
        }
        __syncthreads();
        if (tid < 128) {
            const int bl = tid >> 4, jl = tid & 15;
            const int b = b0 + bl, j = j0 + jl;
            float gi = gate_s[bl][jl * 4 + 0], gf = gate_s[bl][jl * 4 + 1];
            float gg = gate_s[bl][jl * 4 + 2], go = gate_s[bl][jl * 4 + 3];
            float c = g_state[C1OFF + b * NH + j];
            float cn = sigm(gf) * c + sigm(gi) * tanhf(gg);
            g_state[C1OFF + b * NH + j] = cn;
            g_state[H1OFF + cur * (NB * NH) + b * NH + j] = sigm(go) * tanhf(cn);
        }
    } else {
        if (t == 0 || blockIdx.x >= 16) return;
        __shared__ float z_s[4][1200];
        __shared__ float zv_s[4][121];
        out_block(out, t - 1, blockIdx.x * 4, tid, z_s, zv_s);
    }
}

// ---- K2: attention (recomputed per block) + LSTM2 (input=[x,h1,window], K=463+400) ----
__global__ __launch_bounds__(512) void k_step2(
    const int* __restrict__ cseq, const int* __restrict__ clen, int t)
{
    const int tid = threadIdx.x;
    const int cur = t & 1, prev = 1 - cur;
    const int b0 = blockIdx.y * 8;
    const int j0 = blockIdx.x * 16;
    __shared__ float h1_s[8][400], h2p_s[8][400];
    __shared__ float x_s[8][3];
    __shared__ float ab_s[8][30];
    __shared__ float phi_s[8][50];
    __shared__ float win_s[8][60];
    __shared__ float kap_s[8][10];
    __shared__ int   char_s[8][50];
    __shared__ int   len_s[8];
    __shared__ float gate_s[8][64];
    for (int i = tid; i < 8 * 400; i += 512) {
        int bl = i / 400, k = i - bl * 400; int b = b0 + bl;
        h1_s[bl][k]  = g_state[H1OFF + cur  * (NB * NH) + b * NH + k];
        h2p_s[bl][k] = g_state[H2OFF + prev * (NB * NH) + b * NH + k];
    }
    if (tid < 24) { int bl = tid / 3, k = tid - bl * 3;
        x_s[bl][k] = g_W[O_INP + ((b0 + bl) * NT + t) * 3 + k]; }
    if (tid >= 32 && tid < 112) { int i = tid - 32; int bl = i / 10, k = i - bl * 10;
        kap_s[bl][k] = g_state[KPOFF + prev * (NB * NKATT) + (b0 + bl) * NKATT + k]; }
    if (tid >= 112) { int i = tid - 112;
        if (i < 400) { int bl = i / 50, u = i - bl * 50;
            char_s[bl][u] = cseq[(b0 + bl) * NTC + u]; } }
    if (tid < 8) len_s[tid] = clen[b0 + tid];
    __syncthreads();
    if (tid < 240) {            // p = exp(h1 @ W_att.T + b_att)
        int bl = tid / 30, i = tid - bl * 30;
        float acc = g_W[O_BATT + i];
        const float* w = g_W + O_WATT + i * NH;
        const float* hp = h1_s[bl];
        for (int k = 0; k < NH; ++k) acc += w[k] * hp[k];
        ab_s[bl][i] = expf(acc);
    }
    __syncthreads();
    if (tid < 400) {            // phi, masked by length
        int bl = tid / 50, u = tid - bl * 50;
        float ph = 0.f;
        if (u < len_s[bl]) {
            float uf = (float)u;
            for (int k = 0; k < 10; ++k) {
                float kn = kap_s[bl][k] + ab_s[bl][20 + k];
                float d = kn - uf;
                ph += ab_s[bl][k] * expf(-ab_s[bl][10 + k] * d * d);
            }
        }
        phi_s[bl][u] = ph;
    }
    if (blockIdx.x == 0 && tid >= 416 && tid < 496) {   // kappa[cur] writer
        int i = tid - 416; int bl = i / 10, k = i - bl * 10;
        g_state[KPOFF + cur * (NB * NKATT) + (b0 + bl) * NKATT + k] = kap_s[bl][k] + ab_s[bl][20 + k];
    }
    __syncthreads();
    if (tid < 480) {            // window = phi @ one_hot(char)
        int bl = tid / 60, a = tid - bl * 60;
        float wv = 0.f;
        for (int u = 0; u < NTC; ++u) if (char_s[bl][u] == a) wv += phi_s[bl][u];
        win_s[bl][a] = wv;
        if (blockIdx.x == 0) g_state[WINOFF + (b0 + bl) * NALPHA + a] = wv;
    }
    __syncthreads();
    {
        const int bl = tid >> 6, r = tid & 63, jl = r >> 2, g = r & 3;
        const int row = g * NH + j0 + jl;
        float acc = g_W[O_BIH2 + row] + g_W[O_BHH2 + row];
        const float* wi = g_W + O_WIH2 + row * 463;
        acc += wi[0] * x_s[bl][0] + wi[1] * x_s[bl][1] + wi[2] * x_s[bl][2];
        const float* hp = h1_s[bl];
        #pragma unroll 4
        for (int k = 0; k < 400; ++k) acc += wi[3 + k] * hp[k];
        const float* wp = win_s[bl];
        for (int k = 0; k < 60; ++k) acc += wi[403 + k] * wp[k];
        const float* wh = g_W + O_WHH2 + row * NH;
        const float* h2p = h2p_s[bl];
        #pragma unroll 4
        for (int k = 0; k < 400; ++k) acc += wh[k] * h2p[k];
        gate_s[bl][r] = acc;
    }
    __syncthreads();
    if (tid < 128) {
        const int bl = tid >> 4, jl = tid & 15;
        const int b = b0 + bl, j = j0 + jl;
        float gi = gate_s[bl][jl * 4 + 0], gf = gate_s[bl][jl * 4 + 1];
        float gg = gate_s[bl][jl * 4 + 2], go = gate_s[bl][jl * 4 + 3];
        float c = g_state[C2OFF + b * NH + j];
        float cn = sigm(gf) * c + sigm(gi) * tanhf(gg);
        g_state[C2OFF + b * NH + j] = cn;
        g_state[H2OFF + cur * (NB * NH) + b * NH + j] = sigm(go) * tanhf(cn);
    }
}

// ---- K3: LSTM3 (input=[x,h1,h2,window], K=863+400) ----
__global__ __launch_bounds__(512) void k_step3(int t)
{
    const int tid = threadIdx.x;
    const int cur = t & 1, prev = 1 - cur;
    const int b0 = blockIdx.y * 8;
    const int j0 = blockIdx.x * 16;
    __shared__ float h1_s[8][400], h2_s[8][400], h3p_s[8][400];
    __shared__ float x_s[8][3];
    __shared__ float win_s[8][60];
    __shared__ float gate_s[8][64];
    for (int i = tid; i < 8 * 400; i += 512) {
        int bl = i / 400, k = i - bl * 400; int b = b0 + bl;
        h1_s[bl][k]  = g_state[H1OFF + cur  * (NB * NH) + b * NH + k];
        h2_s[bl][k]  = g_state[H2OFF + cur  * (NB * NH) + b * NH + k];
        h3p_s[bl][k] = g_state[H3OFF + prev * (NB * NH) + b * NH + k];
    }
    for (int i = tid; i < 480; i += 512) { int bl = i / 60, a = i - bl * 60;
        win_s[bl][a] = g_state[WINOFF + (b0 + bl) * NALPHA + a]; }
    if (tid < 24) { int bl = tid / 3, k = tid - bl * 3;
        x_s[bl][k] = g_W[O_INP + ((b0 + bl) * NT + t) * 3 + k]; }
    __syncthreads();
    {
        const int bl = tid >> 6, r = tid & 63, jl = r >> 2, g = r & 3;
        const int row = g * NH + j0 + jl;
        float acc = g_W[O_BIH3 + row] + g_W[O_BHH3 + row];
        const float* wi = g_W + O_WIH3 + row * 863;
        acc += wi[0] * x_s[bl][0] + wi[1] * x_s[bl][1] + wi[2] * x_s[bl][2];
        const float* h1p = h1_s[bl];
        #pragma unroll 4
        for (int k = 0; k < 400; ++k) acc += wi[3 + k] * h1p[k];
        const float* h2p = h2_s[bl];
        #pragma unroll 4
        for (int k = 0; k < 400; ++k) acc += wi[403 + k] * h2p[k];
        const float* wp = win_s[bl];
        for (int k = 0; k < 60; ++k) acc += wi[803 + k] * wp[k];
        const float* wh = g_W + O_WHH3 + row * NH;
        const float* h3p = h3p_s[bl];
        #pragma unroll 4
        for (int k = 0; k < 400; ++k) acc += wh[k] * h3p[k];
        gate_s[bl][r] = acc;
    }
    __syncthreads();
    if (tid < 128) {
        const int bl = tid >> 4, jl = tid & 15;
        const int b = b0 + bl, j = j0 + jl;
        float gi = gate_s[bl][jl * 4 + 0], gf = gate_s[bl][jl * 4 + 1];
        float gg = gate_s[bl][jl * 4 + 2], go = gate_s[bl][jl * 4 + 3];
        float c = g_state[C3OFF + b * NH + j];
        float cn = sigm(gf) * c + sigm(gi) * tanhf(gg);
        g_state[C3OFF + b * NH + j] = cn;
        g_state[H3OFF + cur * (NB * NH) + b * NH + j] = sigm(go) * tanhf(cn);
    }
}

// ---- final output head for t = NT-1 ----
__global__ __launch_bounds__(512) void k_out_final(void* out)
{
    __shared__ float z_s[4][1200];
    __shared__ float zv_s[4][121];
    out_block(out, NT - 1, blockIdx.x * 4, threadIdx.x, z_s, zv_s);
}

extern "C" void kernel_launch(void* const* d_in, const int* in_sizes, int n_in,
                              void* d_out, int out_size, void* d_ws, size_t ws_size,
                              hipStream_t stream)
{
    hipLaunchKernelGGL(k_detect, dim3(1), dim3(64), 0, stream, d_in[5]);  // W_hh1
    hipLaunchKernelGGL(k_convert, dim3(1024), dim3(256), 0, stream,
                       d_in[0],
                       d_in[3], d_in[4], d_in[5], d_in[6],
                       d_in[7], d_in[8], d_in[9], d_in[10],
                       d_in[11], d_in[12], d_in[13], d_in[14],
                       d_in[15], d_in[16], d_in[17], d_in[18]);
    const int* cseq = (const int*)d_in[1];
    const int* clen = (const int*)d_in[2];
    for (int t = 0; t < NT; ++t) {
        hipLaunchKernelGGL(k_step1, dim3(25, 9), dim3(512), 0, stream, d_out, t);
        hipLaunchKernelGGL(k_step2, dim3(25, 8), dim3(512), 0, stream, cseq, clen, t);
        hipLaunchKernelGGL(k_step3, dim3(25, 8), dim3(512), 0, stream, t);
    }
    hipLaunchKernelGGL(k_out_final, dim3(16), dim3(512), 0, stream, d_out);
}

// Round 3
// 80982.428 us; speedup vs baseline: 1.7609x; 1.7609x over previous
//
#include <hip/hip_runtime.h>
#include <hip/hip_bf16.h>

#define NB 64
#define NT 600
#define NTC 50
#define NH 400
#define NKATT 10
#define NALPHA 60
#define NOUT 121

typedef unsigned short u16;
typedef _Float16 f16x2 __attribute__((ext_vector_type(2)));
typedef _Float16 f16x4 __attribute__((ext_vector_type(4)));

#if defined(__has_builtin)
#if __has_builtin(__builtin_amdgcn_fdot2)
#define FDOT2(a,b,c) __builtin_amdgcn_fdot2((a),(b),(c),false)
#endif
#endif
#ifndef FDOT2
#define FDOT2(a,b,c) ((c) + (float)(a)[0]*(float)(b)[0] + (float)(a)[1]*(float)(b)[1])
#endif

// Padded fused-K sizes (pairs): K1=512->256, K2=896->448, K3=1280->640. Rows padded 1600->1664.
#define ROWSP 1664

// state layout (floats)
#define H1OFF 0            // [2][NB][NH] ping-pong
#define H2OFF 51200
#define H3OFF 102400
#define C1OFF 153600
#define C2OFF 179200
#define C3OFF 204800
#define KPOFF 230400       // [2][NB][NKATT]
#define WINOFF 231680      // [NB][NALPHA]
#define ST_FLOATS 235520

__device__ __align__(16) f16x2 g_WT1[256 * ROWSP];
__device__ __align__(16) f16x2 g_WT2[448 * ROWSP];
__device__ __align__(16) f16x2 g_WT3[640 * ROWSP];
__device__ __align__(16) f16x2 g_WG2[600 * 128];
__device__ __align__(16) float g_fb1[ROWSP], g_fb2[ROWSP], g_fb3[ROWSP];
__device__ __align__(16) float g_WattT[400 * 32];
__device__ float g_batt[30], g_bgmm[121];
__device__ __align__(16) float g_inp[115200];
__device__ float g_state[ST_FLOATS];
__device__ int   g_isf32;

__device__ __forceinline__ float bf2f(u16 v) {
    union { unsigned int u; float f; } t; t.u = ((unsigned int)v) << 16; return t.f;
}
__device__ __forceinline__ u16 f2bf(float f) {
    union { float ff; unsigned int u; } t; t.ff = f;
    unsigned int lsb = (t.u >> 16) & 1u;
    t.u += 0x7fffu + lsb;
    return (u16)(t.u >> 16);
}
__device__ __forceinline__ float sigm(float x) { return 1.f / (1.f + expf(-x)); }
__device__ __forceinline__ f16x2 packpair(float a, float b) {
    f16x2 r; r[0] = (_Float16)a; r[1] = (_Float16)b; return r;
}

__global__ void k_detect(const void* whh1) {
    if (threadIdx.x == 0 && blockIdx.x == 0) {
        const u16* p = (const u16*)whh1;
        int f32 = 0;
        for (int k = 0; k < 256; ++k) {
            float v = bf2f(p[2 * k]);
            if (!(fabsf(v) < 1e3f)) f32 = 1;
        }
        g_isf32 = f32;
    }
}

// Build fused/transposed/permuted f16 weights + biases; canonicalize inputs; zero state.
__global__ void k_convert(const void* inp,
                          const void* wih1, const void* bih1, const void* whh1, const void* bhh1,
                          const void* wih2, const void* bih2, const void* whh2, const void* bhh2,
                          const void* wih3, const void* bih3, const void* whh3, const void* bhh3,
                          const void* watt, const void* batt, const void* wgmm, const void* bgmm)
{
    const int gt = blockIdx.x * blockDim.x + threadIdx.x;
    const int gs = gridDim.x * blockDim.x;
    const int f32 = g_isf32;
    auto ld = [f32](const void* p, int i) -> float {
        return f32 ? ((const float*)p)[i] : bf2f(((const u16*)p)[i]);
    };
    // fused-K column maps (kf -> source element), row = original gate-major row
    auto w1col = [&](int kf, int row) -> float {
        if (kf < 400) return ld(whh1, row * 400 + kf);          // h1_prev
        if (kf < 460) return ld(wih1, row * 63 + (kf - 400));   // window
        if (kf < 463) return ld(wih1, row * 63 + 60 + (kf - 460)); // x
        return 0.f;
    };
    auto w2col = [&](int kf, int row) -> float {
        if (kf < 400) return ld(wih2, row * 463 + 3 + kf);        // h1
        if (kf < 800) return ld(whh2, row * 400 + (kf - 400));    // h2_prev
        if (kf < 860) return ld(wih2, row * 463 + 403 + (kf - 800)); // window
        if (kf < 863) return ld(wih2, row * 463 + (kf - 860));    // x
        return 0.f;
    };
    auto w3col = [&](int kf, int row) -> float {
        if (kf < 400)  return ld(wih3, row * 863 + 3 + kf);        // h1
        if (kf < 800)  return ld(wih3, row * 863 + 403 + (kf - 400)); // h2
        if (kf < 1200) return ld(whh3, row * 400 + (kf - 800));    // h3_prev
        if (kf < 1260) return ld(wih3, row * 863 + 803 + (kf - 1200)); // window
        if (kf < 1263) return ld(wih3, row * 863 + (kf - 1260));   // x
        return 0.f;
    };
    for (int i = gt; i < 256 * ROWSP; i += gs) {
        int k2 = i / ROWSP, rp = i % ROWSP;
        int j = rp >> 2, g = rp & 3;
        float a = 0.f, b = 0.f;
        if (j < 400) { int row = g * 400 + j; a = w1col(2 * k2, row); b = w1col(2 * k2 + 1, row); }
        g_WT1[i] = packpair(a, b);
    }
    for (int i = gt; i < 448 * ROWSP; i += gs) {
        int k2 = i / ROWSP, rp = i % ROWSP;
        int j = rp >> 2, g = rp & 3;
        float a = 0.f, b = 0.f;
        if (j < 400) { int row = g * 400 + j; a = w2col(2 * k2, row); b = w2col(2 * k2 + 1, row); }
        g_WT2[i] = packpair(a, b);
    }
    for (int i = gt; i < 640 * ROWSP; i += gs) {
        int k2 = i / ROWSP, rp = i % ROWSP;
        int j = rp >> 2, g = rp & 3;
        float a = 0.f, b = 0.f;
        if (j < 400) { int row = g * 400 + j; a = w3col(2 * k2, row); b = w3col(2 * k2 + 1, row); }
        g_WT3[i] = packpair(a, b);
    }
    for (int i = gt; i < ROWSP; i += gs) {
        int j = i >> 2, g = i & 3;
        float b1 = 0.f, b2 = 0.f, b3 = 0.f;
        if (j < 400) {
            int row = g * 400 + j;
            b1 = ld(bih1, row) + ld(bhh1, row);
            b2 = ld(bih2, row) + ld(bhh2, row);
            b3 = ld(bih3, row) + ld(bhh3, row);
        }
        g_fb1[i] = b1; g_fb2[i] = b2; g_fb3[i] = b3;
    }
    for (int i = gt; i < 400 * 32; i += gs) {
        int k = i / 32, r = i % 32;
        g_WattT[i] = (r < 30) ? ld(watt, r * 400 + k) : 0.f;
    }
    for (int i = gt; i < 600 * 128; i += gs) {
        int k2 = i / 128, r = i % 128;
        float a = 0.f, b = 0.f;
        if (r < 121) { a = ld(wgmm, r * 1200 + 2 * k2); b = ld(wgmm, r * 1200 + 2 * k2 + 1); }
        g_WG2[i] = packpair(a, b);
    }
    for (int i = gt; i < 30; i += gs)  g_batt[i] = ld(batt, i);
    for (int i = gt; i < 121; i += gs) g_bgmm[i] = ld(bgmm, i);
    for (int i = gt; i < 115200; i += gs) g_inp[i] = ld(inp, i);
    for (int i = gt; i < ST_FLOATS; i += gs) g_state[i] = 0.f;
}

// Generic LSTM: block = 8 waves; waves split K; lane = 2 rows x 8 batches; LDS reduce; cell update.
template<int KP2>
__device__ __forceinline__ void lstm_core(const f16x2* __restrict__ WT, const float* __restrict__ fb,
                                          float* __restrict__ cst, float* __restrict__ hdst,
                                          const f16x2* inb, float* accS, int rg, int bg, int tid)
{
    const int wv = tid >> 6, lane = tid & 63;
    const int ck = KP2 >> 3;
    const int k0 = wv * ck, kend = k0 + ck;
    const int rbase = rg * 128 + lane * 2;
    float acc[2][8];
    #pragma unroll
    for (int r = 0; r < 2; ++r)
        #pragma unroll
        for (int b = 0; b < 8; ++b) acc[r][b] = 0.f;
    #pragma unroll 4
    for (int k2 = k0; k2 < kend; ++k2) {
        f16x4 w4 = *(const f16x4*)(WT + (size_t)k2 * ROWSP + rbase);
        f16x2 wa; wa[0] = w4[0]; wa[1] = w4[1];
        f16x2 wb; wb[0] = w4[2]; wb[1] = w4[3];
        #pragma unroll
        for (int b = 0; b < 8; ++b) {
            f16x2 hv = inb[b * KP2 + k2];
            acc[0][b] = FDOT2(wa, hv, acc[0][b]);
            acc[1][b] = FDOT2(wb, hv, acc[1][b]);
        }
    }
    #pragma unroll
    for (int r = 0; r < 2; ++r)
        #pragma unroll
        for (int b = 0; b < 8; ++b)
            atomicAdd(&accS[(lane * 2 + r) * 9 + b], acc[r][b]);
    __syncthreads();
    if (tid < 256) {
        int bl = tid >> 5, jj = tid & 31;
        int j = rg * 32 + jj;
        if (j < 400) {
            int rl = jj * 4;
            float gi = accS[(rl + 0) * 9 + bl] + fb[rg * 128 + rl + 0];
            float gf = accS[(rl + 1) * 9 + bl] + fb[rg * 128 + rl + 1];
            float gg = accS[(rl + 2) * 9 + bl] + fb[rg * 128 + rl + 2];
            float go = accS[(rl + 3) * 9 + bl] + fb[rg * 128 + rl + 3];
            int b = bg * 8 + bl;
            float c = cst[b * 400 + j];
            float cn = sigm(gf) * c + sigm(gi) * tanhf(gg);
            cst[b * 400 + j] = cn;
            hdst[b * 400 + j] = sigm(go) * tanhf(cn);
        }
    }
}

// GMM output head: 4 batches per block, coalesced transposed f16 weights, dot2.
__device__ void out_head(void* out, int tOut, int obid, int tid, char* smem)
{
    f16x2* zb = (f16x2*)smem;            // 4*600*4 = 9600
    float* zv = (float*)(smem + 9600);   // 4*121*4 = 1936
    const int pp = tOut & 1;
    const float* h1 = g_state + H1OFF + pp * (NB * NH);
    const float* h2 = g_state + H2OFF + pp * (NB * NH);
    const float* h3 = g_state + H3OFF + pp * (NB * NH);
    for (int i = tid; i < 4 * 600; i += 512) {
        int bq = i / 600, p = i % 600; int b = obid * 4 + bq;
        int kf = 2 * p;
        const float* src = (kf < 400) ? (h1 + b * 400 + kf)
                         : (kf < 800) ? (h2 + b * 400 + (kf - 400))
                                      : (h3 + b * 400 + (kf - 800));
        zb[bq * 600 + p] = packpair(src[0], src[1]);
    }
    __syncthreads();
    {
        int bq = tid >> 7, r = tid & 127;
        if (r < 121) {
            float acc = g_bgmm[r];
            const f16x2* zp = zb + bq * 600;
            #pragma unroll 4
            for (int k2 = 0; k2 < 600; ++k2)
                acc = FDOT2(g_WG2[k2 * 128 + r], zp[k2], acc);
            zv[bq * 121 + r] = acc;
        }
    }
    __syncthreads();
    if (tid < 484) {
        int bl = tid / 121, jo = tid - bl * 121;
        const float* z = zv + bl * 121;
        float val;
        if (jo < 20) {
            float m = -1e30f;
            for (int i = 0; i < 20; ++i) m = fmaxf(m, z[1 + i]);
            float s = 0.f;
            for (int i = 0; i < 20; ++i) s += expf(z[1 + i] - m);
            val = expf(z[1 + jo] - m) / s;
        } else if (jo < 60)  val = z[jo + 1];
        else if (jo < 100)   val = expf(z[jo + 1]);
        else if (jo < 120)   val = tanhf(z[jo + 1]);
        else                 val = 1.f / (1.f + expf(-z[0]));
        int idx = ((obid * 4 + bl) * NT + tOut) * NOUT + jo;
        if (g_isf32) ((float*)out)[idx] = val;
        else         ((u16*)out)[idx]  = f2bf(val);
    }
}

// K1: LSTM1 (blocks 0..103) + GMM head for t-1 (blocks 104..119)
__global__ __launch_bounds__(512) void k_step1(void* out, int t)
{
    __shared__ __align__(16) char smem[13056];
    const int tid = threadIdx.x;
    const int bid = blockIdx.x;
    const int cur = t & 1, prev = cur ^ 1;
    if (bid < 104) {
        f16x2* inb = (f16x2*)smem;             // 8*256*4 = 8192
        float* accS = (float*)(smem + 8192);   // 1152*4 = 4608
        const int rg = bid % 13, bg = bid / 13;
        const float* h1p = g_state + H1OFF + prev * (NB * NH);
        for (int i = tid; i < 8 * 256; i += 512) {
            int bl = i >> 8, p = i & 255; int b = bg * 8 + bl;
            float a = 0.f, v = 0.f;
            if (p < 200)      { a = h1p[b * 400 + 2 * p]; v = h1p[b * 400 + 2 * p + 1]; }
            else if (p < 230) { int q = p - 200;
                                a = g_state[WINOFF + b * 60 + 2 * q];
                                v = g_state[WINOFF + b * 60 + 2 * q + 1]; }
            else if (p == 230){ a = g_inp[(b * NT + t) * 3 + 0]; v = g_inp[(b * NT + t) * 3 + 1]; }
            else if (p == 231){ a = g_inp[(b * NT + t) * 3 + 2]; }
            inb[bl * 256 + p] = packpair(a, v);
        }
        for (int i = tid; i < 1152; i += 512) accS[i] = 0.f;
        __syncthreads();
        lstm_core<256>(g_WT1, g_fb1, g_state + C1OFF, g_state + H1OFF + cur * (NB * NH),
                       inb, accS, rg, bg, tid);
    } else {
        if (t == 0) return;
        out_head(out, t - 1, bid - 104, tid, smem);
    }
}

// K2: attention (per-block recompute) + LSTM2
__global__ __launch_bounds__(512) void k_step2(const int* __restrict__ cseq,
                                               const int* __restrict__ clen, int t)
{
    const int tid = threadIdx.x;
    const int cur = t & 1, prev = cur ^ 1;
    const int rg = blockIdx.x % 13, bg = blockIdx.x / 13;
    __shared__ __align__(16) f16x2 inb[8 * 448];
    __shared__ float h1f[8 * 400];
    __shared__ float accS[1152];
    __shared__ float ab[8 * 30];
    __shared__ float phi[8 * 50];
    __shared__ float kap[8 * 10];
    __shared__ int   chs[8 * 50];
    __shared__ int   len[8];
    const float* h1  = g_state + H1OFF + cur  * (NB * NH);
    const float* h2p = g_state + H2OFF + prev * (NB * NH);
    for (int i = tid; i < 8 * 448; i += 512) {
        int bl = i / 448, p = i % 448; int b = bg * 8 + bl;
        float a = 0.f, v = 0.f;
        if (p < 200) {
            a = h1[b * 400 + 2 * p]; v = h1[b * 400 + 2 * p + 1];
            h1f[bl * 400 + 2 * p] = a; h1f[bl * 400 + 2 * p + 1] = v;
        }
        else if (p < 400) { int q = p - 200; a = h2p[b * 400 + 2 * q]; v = h2p[b * 400 + 2 * q + 1]; }
        else if (p == 430){ a = g_inp[(b * NT + t) * 3 + 0]; v = g_inp[(b * NT + t) * 3 + 1]; }
        else if (p == 431){ a = g_inp[(b * NT + t) * 3 + 2]; }
        inb[bl * 448 + p] = packpair(a, v);   // window region [400,430) filled later
    }
    for (int i = tid; i < 1152; i += 512) accS[i] = 0.f;
    if (tid < 80) { int bl = tid / 10, k = tid % 10;
        kap[tid] = g_state[KPOFF + prev * (NB * NKATT) + (bg * 8 + bl) * 10 + k]; }
    else if (tid >= 80 && tid < 480) { int i = tid - 80; int bl = i / 50, u = i % 50;
        chs[bl * 50 + u] = cseq[(bg * 8 + bl) * NTC + u]; }
    else if (tid >= 480 && tid < 488) len[tid - 480] = clen[bg * 8 + (tid - 480)];
    __syncthreads();
    if (tid < 240) {                       // p = exp(h1 @ W_att.T + b_att)
        int bl = tid / 30, rr = tid % 30;
        float acc = g_batt[rr];
        const float* hp = h1f + bl * 400;
        #pragma unroll 4
        for (int k = 0; k < 400; ++k) acc += g_WattT[k * 32 + rr] * hp[k];
        ab[bl * 30 + rr] = expf(acc);
    }
    __syncthreads();
    if (tid < 400) {                       // phi (length-masked)
        int bl = tid / 50, u = tid % 50;
        float ph = 0.f;
        if (u < len[bl]) {
            float uf = (float)u;
            for (int k = 0; k < 10; ++k) {
                float kn = kap[bl * 10 + k] + ab[bl * 30 + 20 + k];
                float d = kn - uf;
                ph += ab[bl * 30 + k] * expf(-ab[bl * 30 + 10 + k] * d * d);
            }
        }
        phi[bl * 50 + u] = ph;
    } else if (tid >= 400 && tid < 480 && rg == 0) {   // kappa writer
        int i = tid - 400; int bl = i / 10, k = i % 10;
        g_state[KPOFF + cur * (NB * NKATT) + (bg * 8 + bl) * 10 + k] =
            kap[bl * 10 + k] + ab[bl * 30 + 20 + k];
    }
    __syncthreads();
    if (tid < 240) {                       // window pairs -> inb + g_state
        int bl = tid / 30, q = tid % 30;
        int a0 = 2 * q, a1 = 2 * q + 1;
        float w0 = 0.f, w1 = 0.f;
        for (int u = 0; u < NTC; ++u) {
            float pv = phi[bl * 50 + u]; int cc = chs[bl * 50 + u];
            if (cc == a0) w0 += pv;
            if (cc == a1) w1 += pv;
        }
        inb[bl * 448 + 400 + q] = packpair(w0, w1);
        if (rg == 0) { int b = bg * 8 + bl;
            g_state[WINOFF + b * 60 + a0] = w0;
            g_state[WINOFF + b * 60 + a1] = w1; }
    }
    __syncthreads();
    lstm_core<448>(g_WT2, g_fb2, g_state + C2OFF, g_state + H2OFF + cur * (NB * NH),
                   inb, accS, rg, bg, tid);
}

// K3: LSTM3
__global__ __launch_bounds__(512) void k_step3(int t)
{
    const int tid = threadIdx.x;
    const int cur = t & 1, prev = cur ^ 1;
    const int rg = blockIdx.x % 13, bg = blockIdx.x / 13;
    __shared__ __align__(16) f16x2 inb[8 * 640];
    __shared__ float accS[1152];
    const float* h1  = g_state + H1OFF + cur  * (NB * NH);
    const float* h2  = g_state + H2OFF + cur  * (NB * NH);
    const float* h3p = g_state + H3OFF + prev * (NB * NH);
    for (int i = tid; i < 8 * 640; i += 512) {
        int bl = i / 640, p = i % 640; int b = bg * 8 + bl;
        float a = 0.f, v = 0.f;
        if (p < 200)      { a = h1[b * 400 + 2 * p];  v = h1[b * 400 + 2 * p + 1]; }
        else if (p < 400) { int q = p - 200; a = h2[b * 400 + 2 * q];  v = h2[b * 400 + 2 * q + 1]; }
        else if (p < 600) { int q = p - 400; a = h3p[b * 400 + 2 * q]; v = h3p[b * 400 + 2 * q + 1]; }
        else if (p < 630) { int q = p - 600;
                            a = g_state[WINOFF + b * 60 + 2 * q];
                            v = g_state[WINOFF + b * 60 + 2 * q + 1]; }
        else if (p == 630){ a = g_inp[(b * NT + t) * 3 + 0]; v = g_inp[(b * NT + t) * 3 + 1]; }
        else if (p == 631){ a = g_inp[(b * NT + t) * 3 + 2]; }
        inb[bl * 640 + p] = packpair(a, v);
    }
    for (int i = tid; i < 1152; i += 512) accS[i] = 0.f;
    __syncthreads();
    lstm_core<640>(g_WT3, g_fb3, g_state + C3OFF, g_state + H3OFF + cur * (NB * NH),
                   inb, accS, rg, bg, tid);
}

__global__ __launch_bounds__(512) void k_out_last(void* out)
{
    __shared__ __align__(16) char smem[13056];
    out_head(out, NT - 1, blockIdx.x, threadIdx.x, smem);
}

extern "C" void kernel_launch(void* const* d_in, const int* in_sizes, int n_in,
                              void* d_out, int out_size, void* d_ws, size_t ws_size,
                              hipStream_t stream)
{
    hipLaunchKernelGGL(k_detect, dim3(1), dim3(64), 0, stream, d_in[5]);  // W_hh1
    hipLaunchKernelGGL(k_convert, dim3(2048), dim3(256), 0, stream,
                       d_in[0],
                       d_in[3], d_in[4], d_in[5], d_in[6],
                       d_in[7], d_in[8], d_in[9], d_in[10],
                       d_in[11], d_in[12], d_in[13], d_in[14],
                       d_in[15], d_in[16], d_in[17], d_in[18]);
    const int* cseq = (const int*)d_in[1];
    const int* clen = (const int*)d_in[2];
    for (int t = 0; t < NT; ++t) {
        hipLaunchKernelGGL(k_step1, dim3(120), dim3(512), 0, stream, d_out, t);
        hipLaunchKernelGGL(k_step2, dim3(104), dim3(512), 0, stream, cseq, clen, t);
        hipLaunchKernelGGL(k_step3, dim3(104), dim3(512), 0, stream, t);
    }
    hipLaunchKernelGGL(k_out_last, dim3(16), dim3(512), 0, stream, d_out);
}